// Round 13
// baseline (4576.492 us; speedup 1.0000x reference)
//
#include <hip/hip_runtime.h>
#include <hip/hip_bf16.h>

#define SDIM 512
#define BDIM 64
#define INDIM 512
#define HDIM 1024
#define OUTDIM 512
#define NWG 256
#define THREADS 512
#define BH (BDIM * HDIM)

typedef __bf16 bfreg;
typedef bfreg bf16x8 __attribute__((ext_vector_type(8)));
typedef bfreg bf16x4 __attribute__((ext_vector_type(4)));
typedef float f32x4 __attribute__((ext_vector_type(4)));
typedef float f32x16 __attribute__((ext_vector_type(16)));

__device__ __forceinline__ float sigf(float x) { return 1.f / (1.f + __expf(-x)); }
__device__ __forceinline__ float tanhfast(float x) { return 1.f - 2.f / (__expf(2.f * x) + 1.f); }

// ---------- preamble kernels ----------

__global__ void cvt_bf16(bfreg* __restrict__ dst, const float* __restrict__ src, int n4)
{
    for (int i = blockIdx.x * blockDim.x + threadIdx.x; i < n4; i += gridDim.x * blockDim.x) {
        const float4 v = *(const float4*)(src + (size_t)i * 4);
        bf16x4 o;
        o[0] = (bfreg)v.x; o[1] = (bfreg)v.y; o[2] = (bfreg)v.z; o[3] = (bfreg)v.w;
        *(bf16x4*)(dst + (size_t)i * 4) = o;
    }
}

__global__ void bias_combine(float* __restrict__ b0, const float* __restrict__ bx0,
                             const float* __restrict__ bh0,
                             float* __restrict__ b1, const float* __restrict__ bx1,
                             const float* __restrict__ bh1)
{
    int i = blockIdx.x * blockDim.x + threadIdx.x;
    if (i < 4 * HDIM) {
        b0[i] = bx0[i] + bh0[i];
        b1[i] = bx1[i] + bh1[i];
    }
}

// Pack x [S][B][IN] fp32 -> chunked bf16 [S][IN/8][B][8]
__global__ void pack_x(bfreg* __restrict__ dst, const float* __restrict__ src)
{
    const int total = SDIM * (INDIM / 8) * BDIM;      // 16B chunks
    for (int idx = blockIdx.x * blockDim.x + threadIdx.x; idx < total;
         idx += gridDim.x * blockDim.x) {
        const int b = idx & (BDIM - 1);
        const int r = idx >> 6;
        const int kb = r & (INDIM / 8 - 1);
        const int t = r >> 6;
        const float* s = src + ((size_t)t * BDIM + b) * INDIM + kb * 8;
        bfreg* d = dst + (size_t)idx * 8;
        #pragma unroll
        for (int j = 0; j < 8; ++j) d[j] = (bfreg)s[j];
    }
}

// Pack W = [Wx | Uh] (row-major fp32) into per-WG 32x32x16 MFMA B-fragment
// order, bf16. dst chunk idx = (wg*KST16 + ks)*64 + lane ; chunk = 8 bf16.
// rr = lane&31; g = rr>>3; uo = rr&7; row = g*HDIM + wg*8 + uo;
// k = ks*16 + (lane>>5)*8 + j.
__global__ void pack_w(bfreg* __restrict__ dst, const float* __restrict__ Wx,
                       const float* __restrict__ Uh, int K0, int KH)
{
    const int KST16 = (K0 + KH) / 16;
    const int total = 128 * KST16 * 64;
    for (int idx = blockIdx.x * blockDim.x + threadIdx.x; idx < total;
         idx += gridDim.x * blockDim.x) {
        const int lane = idx & 63;
        int rem = idx >> 6;
        const int ks = rem % KST16;
        const int wg = rem / KST16;
        const int rr = lane & 31;
        const int g = rr >> 3, uo = rr & 7;
        const int row = g * HDIM + wg * 8 + uo;
        const int k = ks * 16 + (lane >> 5) * 8;
        const float* s = (k < K0) ? Wx + (size_t)row * K0 + k
                                  : Uh + (size_t)row * KH + (k - K0);
        bfreg* d = dst + (size_t)idx * 8;
        #pragma unroll
        for (int j = 0; j < 8; ++j) d[j] = (bfreg)s[j];
    }
}

// ---------- sync helpers ----------
// Per-wave direct gating: wave kq's K-quarter depends on producer WGs
// rg in [kq*32, kq*32+32) = sub lines {2kq, 2kq+1}. Lanes 0/1 poll the two
// 64B-spaced counter lines (same-address lanes coalesce to 2 requests).

__device__ __forceinline__ void wait_sub2(const unsigned* base, int l)
{
    const unsigned* p = base + (l & 1) * 16;
    const bool act = (l < 2);
    while (true) {
        unsigned v = __hip_atomic_load(p, __ATOMIC_RELAXED, __HIP_MEMORY_SCOPE_AGENT);
        if (__all(!act || v >= 16u)) break;
        __builtin_amdgcn_s_sleep(1);
    }
}

// ---------- persistent 2-layer LSTM scan: 32x32x16 core, per-wave gating ----------
// 256 WGs x 512 threads, 1 WG/CU. layer = wgid&1, rg = wgid>>1 (8 h-units =
// 32 gate rows). Waves: wid = kq*2 + m ; m = 32-row batch half, kq =
// CONTIGUOUS K-quarter. Each wave: one 32x32 output tile, acc = f32x16.
// L0: early = x (ks = kq*8+i, no gate); late = h0[t-1] (ks = 32+kq*16+i,
//     gated on sub0[t-1] lines {2kq,2kq+1}).
// L1: late = h0[t] (ks = kq*16+i, gated sub0[t]); early = h1[t-1]
//     (ks = 64+kq*16+i, gated sub1[t-1]).
// 4 K-partials -> two-phase LDS reduction -> epilogue -> per-wave publish;
// publisher wave adds to this WG's sub line after all 8 waves' stores ack.
template<int LAYER>
__device__ __forceinline__ void scan_layer(
    const bfreg* __restrict__ Pw, const float* __restrict__ biasL,
    const bfreg* __restrict__ x_pk,
    bfreg* __restrict__ Hb0, bfreg* __restrict__ Hb1,
    unsigned* __restrict__ sub0, unsigned* __restrict__ sub1,
    const int rg, char* smem)
{
    constexpr int KST16 = LAYER ? 128 : 96;
    constexpr int ECNT = LAYER ? 16 : 8;     // L0: x (ks<32); L1: h1 (ks>=64)
    constexpr int LCNT = 16;                 // L0: h0 (ks 32..95); L1: h0 (ks<64)

    const int tid = threadIdx.x;
    const int l = tid & 63;
    const int wid = tid >> 6;
    const int m = wid & 1;
    const int kq = wid >> 1;

    bfreg* lW = (bfreg*)smem;
    float* gatebuf = (float*)(smem + 128 * 1024);  // [2][32][68]
    float* cbuf = gatebuf + 2 * 32 * 68;           // [8][68]
    float* lbias = cbuf + 8 * 68;                  // [32]
    int* done = (int*)(lbias + 32);                // [1]

    {
        const float4* wsrc = (const float4*)(Pw + (size_t)rg * ((size_t)KST16 * 512));
        float4* wdst = (float4*)lW;
        for (int i = tid; i < KST16 * 64; i += THREADS) wdst[i] = wsrc[i];
    }
    if (tid < 32) lbias[tid] = biasL[(tid >> 3) * HDIM + rg * 8 + (tid & 7)];
    if (tid == 0) *done = 0;
    for (int i = tid; i < 8 * 68; i += THREADS) cbuf[i] = 0.f;
    __syncthreads();

    const int rowA = m * 32 + (l & 31);
    const int k8 = l >> 5;
    const int rr = l & 31;
    const int boff = 4 * (l >> 5);

    unsigned* mysub = LAYER ? sub1 : sub0;
    bfreg* Hme = LAYER ? Hb1 : Hb0;

    for (int t = 0; t < SDIM; ++t) {
        f32x16 acc = {};
        bf16x8 ev[ECNT];
        bf16x8 av[LCNT];

        if (!LAYER) {
            // ---- issue x loads (no gate) ----
            const bfreg* s0 = x_pk + (size_t)t * (64 * BDIM * 8);
            #pragma unroll
            for (int i = 0; i < ECNT; ++i) {
                const int ks = kq * 8 + i;               // < 32
                const int cb = ks * 2 + k8;
                ev[i] = *(const bf16x8*)(s0 + (size_t)cb * 512 + rowA * 8);
            }
            __builtin_amdgcn_sched_barrier(0);
            // ---- gate: own quarter of sub0[t-1] ----
            if (t > 0)
                wait_sub2(sub0 + (size_t)(t - 1) * 128 + 2 * kq * 16, l);
            asm volatile("" ::: "memory");
            // ---- issue h0[t-1] loads ----
            const bfreg* s1 = Hb0 + (size_t)t * BH;
            #pragma unroll
            for (int i = 0; i < LCNT; ++i) {
                const int ks = 32 + kq * 16 + i;         // 32..95
                const int cb = (ks - 32) * 2 + k8;
                av[i] = *(const bf16x8*)(s1 + (size_t)cb * 512 + rowA * 8);
            }
            __builtin_amdgcn_sched_barrier(0);
        } else {
            // ---- gate: own quarter of sub0[t] (L0 leads) ----
            wait_sub2(sub0 + (size_t)t * 128 + 2 * kq * 16, l);
            asm volatile("" ::: "memory");
            // ---- issue h0[t] loads ----
            const bfreg* s0 = Hb0 + (size_t)(t + 1) * BH;
            #pragma unroll
            for (int i = 0; i < LCNT; ++i) {
                const int ks = kq * 16 + i;              // < 64
                const int cb = ks * 2 + k8;
                av[i] = *(const bf16x8*)(s0 + (size_t)cb * 512 + rowA * 8);
            }
            __builtin_amdgcn_sched_barrier(0);
            // ---- gate: own quarter of sub1[t-1] ----
            if (t > 0)
                wait_sub2(sub1 + (size_t)(t - 1) * 128 + 2 * kq * 16, l);
            asm volatile("" ::: "memory");
            // ---- issue h1[t-1] loads ----
            const bfreg* s1 = Hb1 + (size_t)t * BH;
            #pragma unroll
            for (int i = 0; i < ECNT; ++i) {
                const int ks = 64 + kq * 16 + i;         // 64..127
                const int cb = (ks - 64) * 2 + k8;
                ev[i] = *(const bf16x8*)(s1 + (size_t)cb * 512 + rowA * 8);
            }
            __builtin_amdgcn_sched_barrier(0);
        }

        // ---- MFMA blocks (one 32x32x16 per k-step) ----
        if (!LAYER) {
            #pragma unroll
            for (int i = 0; i < ECNT; ++i) {
                const int ks = kq * 8 + i;
                const bf16x8 w = *(const bf16x8*)(lW + ((size_t)ks * 64 + l) * 8);
                acc = __builtin_amdgcn_mfma_f32_32x32x16_bf16(ev[i], w, acc, 0, 0, 0);
            }
            #pragma unroll
            for (int i = 0; i < LCNT; ++i) {
                const int ks = 32 + kq * 16 + i;
                const bf16x8 w = *(const bf16x8*)(lW + ((size_t)ks * 64 + l) * 8);
                acc = __builtin_amdgcn_mfma_f32_32x32x16_bf16(av[i], w, acc, 0, 0, 0);
            }
        } else {
            #pragma unroll
            for (int i = 0; i < LCNT; ++i) {
                const int ks = kq * 16 + i;
                const bf16x8 w = *(const bf16x8*)(lW + ((size_t)ks * 64 + l) * 8);
                acc = __builtin_amdgcn_mfma_f32_32x32x16_bf16(av[i], w, acc, 0, 0, 0);
            }
            #pragma unroll
            for (int i = 0; i < ECNT; ++i) {
                const int ks = 64 + kq * 16 + i;
                const bf16x8 w = *(const bf16x8*)(lW + ((size_t)ks * 64 + l) * 8);
                acc = __builtin_amdgcn_mfma_f32_32x32x16_bf16(ev[i], w, acc, 0, 0, 0);
            }
        }

        // ---- two-phase K-partial reduction in LDS ----
        if (wid >= 4) {
            float* slot = gatebuf + (kq - 2) * (32 * 68);
            #pragma unroll
            for (int q = 0; q < 4; ++q) {
                f32x4 v = { acc[4 * q], acc[4 * q + 1], acc[4 * q + 2], acc[4 * q + 3] };
                *(f32x4*)(slot + rr * 68 + m * 32 + 8 * q + boff) = v;
            }
        }
        __syncthreads();   // [R1]
        if (wid < 4) {
            float* slot = gatebuf + kq * (32 * 68);
            #pragma unroll
            for (int q = 0; q < 4; ++q) {
                float* pp = slot + rr * 68 + m * 32 + 8 * q + boff;
                f32x4 v = *(f32x4*)pp;
                v[0] += acc[4 * q];     v[1] += acc[4 * q + 1];
                v[2] += acc[4 * q + 2]; v[3] += acc[4 * q + 3];
                *(f32x4*)pp = v;
            }
        }
        __syncthreads();   // [A] gates ready

        // ---- epilogue + direct per-wave publish ----
        {
            const int uo = tid & 7, b = tid >> 3;
            float* g0 = gatebuf;
            float* g1 = gatebuf + 32 * 68;
            const float fv = g0[uo * 68 + b]        + g1[uo * 68 + b]        + lbias[uo];
            const float iv = g0[(8 + uo) * 68 + b]  + g1[(8 + uo) * 68 + b]  + lbias[8 + uo];
            const float ov = g0[(16 + uo) * 68 + b] + g1[(16 + uo) * 68 + b] + lbias[16 + uo];
            const float gv = g0[(24 + uo) * 68 + b] + g1[(24 + uo) * 68 + b] + lbias[24 + uo];
            const float c = cbuf[uo * 68 + b];
            const float fg = sigf(fv), ig = sigf(iv), og = sigf(ov);
            const float gg = tanhfast(gv);
            const float cn = fg * c + ig * gg;
            cbuf[uo * 68 + b] = cn;
            const bfreg hv = (bfreg)(og * tanhfast(cn));
            unsigned short hs;
            __builtin_memcpy(&hs, &hv, 2);
            const unsigned hw = hs;
            bfreg* dp = Hme + (size_t)(t + 1) * BH + rg * 512 + tid;
            asm volatile("global_store_short %0, %1, off sc0 sc1"
                         :: "v"(dp), "v"(hw) : "memory");
            asm volatile("s_waitcnt vmcnt(0)" ::: "memory");
        }
        if (l == 0)
            __hip_atomic_fetch_add(done, 1, __ATOMIC_ACQ_REL,
                                   __HIP_MEMORY_SCOPE_WORKGROUP);
        if (wid == 1) {
            // publisher: all 8 waves' h stores acked -> bump this WG's sub line
            while (__hip_atomic_load(done, __ATOMIC_ACQUIRE,
                                     __HIP_MEMORY_SCOPE_WORKGROUP) < 8 * (t + 1))
                __builtin_amdgcn_s_sleep(1);
            if (l == 0)
                __hip_atomic_fetch_add(mysub + (size_t)t * 128 + (rg >> 4) * 16, 1u,
                                       __ATOMIC_RELAXED, __HIP_MEMORY_SCOPE_AGENT);
        }
    }
}

__global__ __launch_bounds__(THREADS, 2)
void lstm_scan(const bfreg* __restrict__ Pw0, const bfreg* __restrict__ Pw1,
               const float* __restrict__ bias0, const float* __restrict__ bias1,
               const bfreg* __restrict__ x_pk,
               bfreg* __restrict__ Hb0, bfreg* __restrict__ Hb1,
               unsigned* __restrict__ sub0, unsigned* __restrict__ sub1)
{
    extern __shared__ char smem[];
    const int wgid = blockIdx.x;
    const int rg = wgid >> 1;
    if (wgid & 1)
        scan_layer<1>(Pw1, bias1, x_pk, Hb0, Hb1, sub0, sub1, rg, smem);
    else
        scan_layer<0>(Pw0, bias0, x_pk, Hb0, Hb1, sub0, sub1, rg, smem);
}

// ---------- FC head ----------
__global__ void fc_gemm(const bfreg* __restrict__ Hb1, const bfreg* __restrict__ Wb,
                        const float* __restrict__ bias, float* __restrict__ out)
{
    const int lane = threadIdx.x & 63;
    const int wid = threadIdx.x >> 6;
    const int cl = lane & 15, kg = lane >> 4;
    const int mbase = blockIdx.y * 64 + (wid >> 1) * 32;
    const int nbase = blockIdx.x * 64 + (wid & 1) * 32;
    const int t = mbase >> 6;
    const int b0 = mbase & 63;
    const bfreg* pa0 = Hb1 + (size_t)(t + 1) * BH + (size_t)kg * 512 + (b0 + cl) * 8;
    const bfreg* pa1 = pa0 + 16 * 8;
    const bfreg* pb0 = Wb + (size_t)(nbase + cl) * HDIM + kg * 8;
    const bfreg* pb1 = pb0 + (size_t)16 * HDIM;
    f32x4 acc[2][2] = {};
    #pragma unroll 4
    for (int k = 0; k < HDIM; k += 32) {
        const size_t co = (size_t)(k >> 3) * 512;
        const bf16x8 av0 = *(const bf16x8*)(pa0 + co);
        const bf16x8 av1 = *(const bf16x8*)(pa1 + co);
        const bf16x8 bv0 = *(const bf16x8*)(pb0 + k);
        const bf16x8 bv1 = *(const bf16x8*)(pb1 + k);
        acc[0][0] = __builtin_amdgcn_mfma_f32_16x16x32_bf16(av0, bv0, acc[0][0], 0, 0, 0);
        acc[0][1] = __builtin_amdgcn_mfma_f32_16x16x32_bf16(av0, bv1, acc[0][1], 0, 0, 0);
        acc[1][0] = __builtin_amdgcn_mfma_f32_16x16x32_bf16(av1, bv0, acc[1][0], 0, 0, 0);
        acc[1][1] = __builtin_amdgcn_mfma_f32_16x16x32_bf16(av1, bv1, acc[1][1], 0, 0, 0);
    }
    #pragma unroll
    for (int mi = 0; mi < 2; ++mi)
        #pragma unroll
        for (int ni = 0; ni < 2; ++ni)
            #pragma unroll
            for (int r = 0; r < 4; ++r) {
                const int row = mbase + mi * 16 + kg * 4 + r;
                const int col = nbase + ni * 16 + cl;
                out[(size_t)row * OUTDIM + col] = acc[mi][ni][r] + bias[col];
            }
}

extern "C" void kernel_launch(void* const* d_in, const int* in_sizes, int n_in,
                              void* d_out, int out_size, void* d_ws, size_t ws_size,
                              hipStream_t stream)
{
    const float* x     = (const float*)d_in[0];
    const float* l0_Wx = (const float*)d_in[1];
    const float* l0_Uh = (const float*)d_in[2];
    const float* l0_bx = (const float*)d_in[3];
    const float* l0_bh = (const float*)d_in[4];
    const float* l1_Wx = (const float*)d_in[5];
    const float* l1_Uh = (const float*)d_in[6];
    const float* l1_bx = (const float*)d_in[7];
    const float* l1_bh = (const float*)d_in[8];
    const float* fc_W  = (const float*)d_in[9];
    const float* fc_b  = (const float*)d_in[10];
    (void)in_sizes; (void)n_in; (void)out_size; (void)ws_size;

    char* p = (char*)d_ws;
    size_t off = 0;
    auto take = [&](size_t bytes) {
        void* r = p + off;
        off = (off + bytes + 255) & ~(size_t)255;
        return r;
    };

    bfreg* x_pk  = (bfreg*)take((size_t)SDIM * BDIM * INDIM * 2);
    bfreg* Pw0   = (bfreg*)take((size_t)128 * 96 * 512 * 2);    // [wg][ks16][64 lanes x 8]
    bfreg* Pw1   = (bfreg*)take((size_t)128 * 128 * 512 * 2);
    bfreg* fcWb  = (bfreg*)take((size_t)OUTDIM * HDIM * 2);
    float* bias0 = (float*)take((size_t)4 * HDIM * 4);
    float* bias1 = (float*)take((size_t)4 * HDIM * 4);
    bfreg* Hb0   = (bfreg*)take((size_t)(SDIM + 1) * BH * 2);
    bfreg* Hb1   = (bfreg*)take((size_t)(SDIM + 1) * BH * 2);
    unsigned* sub0 = (unsigned*)take((size_t)SDIM * 128 * 4);   // [t][8 lines x 16]
    unsigned* sub1 = (unsigned*)take((size_t)SDIM * 128 * 4);

    // deterministic per-call init
    hipMemsetAsync(Hb0, 0, (size_t)BH * 2, stream);
    hipMemsetAsync(Hb1, 0, (size_t)BH * 2, stream);
    hipMemsetAsync(sub0, 0, (size_t)SDIM * 128 * 4, stream);
    hipMemsetAsync(sub1, 0, (size_t)SDIM * 128 * 4, stream);

    pack_x<<<4096, 256, 0, stream>>>(x_pk, x);
    cvt_bf16<<<512, 256, 0, stream>>>(fcWb, fc_W, OUTDIM * HDIM / 4);
    pack_w<<<3072, 256, 0, stream>>>(Pw0, l0_Wx, l0_Uh, INDIM, HDIM);
    pack_w<<<4096, 256, 0, stream>>>(Pw1, l1_Wx, l1_Uh, HDIM, HDIM);
    bias_combine<<<16, 256, 0, stream>>>(bias0, l0_bx, l0_bh, bias1, l1_bx, l1_bh);

    const int smem_bytes = 128 * 1024 + 2 * 32 * 68 * 4 + 8 * 68 * 4 + 32 * 4 + 16;
    hipFuncSetAttribute((const void*)lstm_scan,
                        hipFuncAttributeMaxDynamicSharedMemorySize, smem_bytes);
    lstm_scan<<<NWG, THREADS, smem_bytes, stream>>>(Pw0, Pw1, bias0, bias1,
                                                    x_pk, Hb0, Hb1, sub0, sub1);

    fc_gemm<<<dim3(OUTDIM / 64, SDIM * BDIM / 64), 256, 0, stream>>>(
        Hb1, fcWb, fc_b, (float*)d_out);
}

// Round 14
// 3217.115 us; speedup vs baseline: 1.4225x; 1.4225x over previous
//
#include <hip/hip_runtime.h>
#include <hip/hip_bf16.h>

#define SDIM 512
#define BDIM 64
#define INDIM 512
#define HDIM 1024
#define OUTDIM 512
#define NWG 256
#define THREADS 512
#define BH (BDIM * HDIM)

typedef __bf16 bfreg;
typedef bfreg bf16x8 __attribute__((ext_vector_type(8)));
typedef bfreg bf16x4 __attribute__((ext_vector_type(4)));
typedef float f32x4 __attribute__((ext_vector_type(4)));
typedef float f32x16 __attribute__((ext_vector_type(16)));

__device__ __forceinline__ float sigf(float x) { return 1.f / (1.f + __expf(-x)); }
__device__ __forceinline__ float tanhfast(float x) { return 1.f - 2.f / (__expf(2.f * x) + 1.f); }

// ---------- preamble kernels ----------

__global__ void cvt_bf16(bfreg* __restrict__ dst, const float* __restrict__ src, int n4)
{
    for (int i = blockIdx.x * blockDim.x + threadIdx.x; i < n4; i += gridDim.x * blockDim.x) {
        const float4 v = *(const float4*)(src + (size_t)i * 4);
        bf16x4 o;
        o[0] = (bfreg)v.x; o[1] = (bfreg)v.y; o[2] = (bfreg)v.z; o[3] = (bfreg)v.w;
        *(bf16x4*)(dst + (size_t)i * 4) = o;
    }
}

__global__ void bias_combine(float* __restrict__ b0, const float* __restrict__ bx0,
                             const float* __restrict__ bh0,
                             float* __restrict__ b1, const float* __restrict__ bx1,
                             const float* __restrict__ bh1)
{
    int i = blockIdx.x * blockDim.x + threadIdx.x;
    if (i < 4 * HDIM) {
        b0[i] = bx0[i] + bh0[i];
        b1[i] = bx1[i] + bh1[i];
    }
}

// Pack x [S][B][IN] fp32 -> chunked bf16 [S][IN/8][B][8]
__global__ void pack_x(bfreg* __restrict__ dst, const float* __restrict__ src)
{
    const int total = SDIM * (INDIM / 8) * BDIM;      // 16B chunks
    for (int idx = blockIdx.x * blockDim.x + threadIdx.x; idx < total;
         idx += gridDim.x * blockDim.x) {
        const int b = idx & (BDIM - 1);
        const int r = idx >> 6;
        const int kb = r & (INDIM / 8 - 1);
        const int t = r >> 6;
        const float* s = src + ((size_t)t * BDIM + b) * INDIM + kb * 8;
        bfreg* d = dst + (size_t)idx * 8;
        #pragma unroll
        for (int j = 0; j < 8; ++j) d[j] = (bfreg)s[j];
    }
}

// Pack W = [Wx | Uh] (row-major fp32) into per-WG 32x32x16 MFMA B-fragment
// order, bf16. dst chunk idx = (wg*KST16 + ks)*64 + lane ; chunk = 8 bf16.
// rr = lane&31; g = rr>>3; uo = rr&7; row = g*HDIM + wg*8 + uo;
// k = ks*16 + (lane>>5)*8 + j.
__global__ void pack_w(bfreg* __restrict__ dst, const float* __restrict__ Wx,
                       const float* __restrict__ Uh, int K0, int KH)
{
    const int KST16 = (K0 + KH) / 16;
    const int total = 128 * KST16 * 64;
    for (int idx = blockIdx.x * blockDim.x + threadIdx.x; idx < total;
         idx += gridDim.x * blockDim.x) {
        const int lane = idx & 63;
        int rem = idx >> 6;
        const int ks = rem % KST16;
        const int wg = rem / KST16;
        const int rr = lane & 31;
        const int g = rr >> 3, uo = rr & 7;
        const int row = g * HDIM + wg * 8 + uo;
        const int k = ks * 16 + (lane >> 5) * 8;
        const float* s = (k < K0) ? Wx + (size_t)row * K0 + k
                                  : Uh + (size_t)row * KH + (k - K0);
        bfreg* d = dst + (size_t)idx * 8;
        #pragma unroll
        for (int j = 0; j < 8; ++j) d[j] = (bfreg)s[j];
    }
}

// ---------- sync helpers ----------
// Producers: publisher wave RMWs 1 of 8 sub lines (16 producers each).
// Consumers: ONE poller wave per dependency polls all 8 sub lines directly
// (lanes 0-7, one coalesced 8-request round) then sets an LDS ready flag the
// other 7 waves spin on. (r12 minus the aggregator/gen hops.)

__device__ __forceinline__ void wait_sub8(const unsigned* base, int l)
{
    const unsigned* p = base + (l & 7) * 16;
    while (true) {
        unsigned v = (l < 8)
            ? __hip_atomic_load(p, __ATOMIC_RELAXED, __HIP_MEMORY_SCOPE_AGENT)
            : 16u;
        if (__all(v >= 16u)) break;
        __builtin_amdgcn_s_sleep(1);
    }
}

__device__ __forceinline__ void lds_spin(int* r, int target)
{
    while (__hip_atomic_load(r, __ATOMIC_ACQUIRE, __HIP_MEMORY_SCOPE_WORKGROUP) < target)
        __builtin_amdgcn_s_sleep(1);
}

// ---------- persistent 2-layer LSTM scan: 32x32x16 MFMA core ----------
// 256 WGs x 512 threads, 1 WG/CU. layer = wgid&1, rg = wgid>>1 (8 h-units =
// 32 gate rows = one 32-wide ntile). Waves: wid = kq*2 + m ; m = 32-row batch
// half, kq = strided K-quarter (ks = kq + 4*i). Each wave: one 32x32 output
// tile, acc = f32x16. 4 K-partials -> two-phase LDS reduction (kq>=2 store,
// barrier, kq<2 RMW-add, barrier) -> epilogue.
// A-frag: row = m*32+(lane&31), k-octet = lane>>5. B from LDS packed order.
// C/D: col(rr) = lane&31, row(b in 32) = (r&3)+8*(r>>2)+4*(lane>>5).
template<int LAYER>
__device__ __forceinline__ void scan_layer(
    const bfreg* __restrict__ Pw, const float* __restrict__ biasL,
    const bfreg* __restrict__ x_pk,
    bfreg* __restrict__ Hb0, bfreg* __restrict__ Hb1,
    unsigned* __restrict__ sub0, unsigned* __restrict__ sub1,
    const int rg, char* smem)
{
    constexpr int KST16 = LAYER ? 128 : 96;
    constexpr int ECNT = LAYER ? 16 : 8;     // L0: x (ks<32); L1: h1 (ks>=64)
    constexpr int LCNT = 16;                 // L0: h0 (ks 32..95); L1: h0 (ks<64)

    const int tid = threadIdx.x;
    const int l = tid & 63;
    const int wid = tid >> 6;
    const int m = wid & 1;
    const int kq = wid >> 1;

    bfreg* lW = (bfreg*)smem;
    float* gatebuf = (float*)(smem + 128 * 1024);  // [2][32][68]
    float* cbuf = gatebuf + 2 * 32 * 68;           // [8][68]
    float* lbias = cbuf + 8 * 68;                  // [32]
    int* ready = (int*)(lbias + 32);               // [0],[1] gates, [2] done

    {
        const float4* wsrc = (const float4*)(Pw + (size_t)rg * ((size_t)KST16 * 512));
        float4* wdst = (float4*)lW;
        for (int i = tid; i < KST16 * 64; i += THREADS) wdst[i] = wsrc[i];
    }
    if (tid < 32) lbias[tid] = biasL[(tid >> 3) * HDIM + rg * 8 + (tid & 7)];
    if (tid < 3) ready[tid] = 0;
    for (int i = tid; i < 8 * 68; i += THREADS) cbuf[i] = 0.f;
    __syncthreads();

    const int rowA = m * 32 + (l & 31);
    const int k8 = l >> 5;
    const int rr = l & 31;
    const int boff = 4 * (l >> 5);

    unsigned* mysub = LAYER ? sub1 : sub0;
    bfreg* Hme = LAYER ? Hb1 : Hb0;
    int* done = ready + 2;

    for (int t = 0; t < SDIM; ++t) {
        f32x16 acc = {};
        bf16x8 ev[ECNT];
        bf16x8 av[LCNT];

        if (!LAYER) {
            // ---- issue x loads (no gate) ----
            const bfreg* s0 = x_pk + (size_t)t * (64 * BDIM * 8);
            #pragma unroll
            for (int i = 0; i < ECNT; ++i) {
                const int ks = kq + 4 * i;               // < 32
                const int cb = ks * 2 + k8;
                ev[i] = *(const bf16x8*)(s0 + (size_t)cb * 512 + rowA * 8);
            }
            __builtin_amdgcn_sched_barrier(0);
            // ---- gate: sub0[t-1] all-16 (poller wave 0, direct) ----
            if (t > 0) {
                if (wid == 0) {
                    wait_sub8(sub0 + (size_t)(t - 1) * 128, l);
                    __hip_atomic_store(&ready[0], t, __ATOMIC_RELEASE,
                                       __HIP_MEMORY_SCOPE_WORKGROUP);
                } else {
                    lds_spin(&ready[0], t);
                }
            }
            asm volatile("" ::: "memory");
            // ---- issue h0[t-1] loads ----
            const bfreg* s1 = Hb0 + (size_t)t * BH;
            #pragma unroll
            for (int i = 0; i < LCNT; ++i) {
                const int ks = kq + 4 * (8 + i);         // 32..95
                const int cb = (ks - 32) * 2 + k8;
                av[i] = *(const bf16x8*)(s1 + (size_t)cb * 512 + rowA * 8);
            }
            __builtin_amdgcn_sched_barrier(0);
        } else {
            // ---- gate: sub0[t] all-16 (L0 leads; poller wave 0, direct) ----
            if (wid == 0) {
                wait_sub8(sub0 + (size_t)t * 128, l);
                __hip_atomic_store(&ready[0], t + 1, __ATOMIC_RELEASE,
                                   __HIP_MEMORY_SCOPE_WORKGROUP);
            } else {
                lds_spin(&ready[0], t + 1);
            }
            asm volatile("" ::: "memory");
            // ---- issue h0[t] loads ----
            const bfreg* s0 = Hb0 + (size_t)(t + 1) * BH;
            #pragma unroll
            for (int i = 0; i < LCNT; ++i) {
                const int ks = kq + 4 * i;               // < 64
                const int cb = ks * 2 + k8;
                av[i] = *(const bf16x8*)(s0 + (size_t)cb * 512 + rowA * 8);
            }
            __builtin_amdgcn_sched_barrier(0);
            // ---- gate: sub1[t-1] all-16 (poller wave 4, direct) ----
            if (t > 0) {
                if (wid == 4) {
                    wait_sub8(sub1 + (size_t)(t - 1) * 128, l);
                    __hip_atomic_store(&ready[1], t, __ATOMIC_RELEASE,
                                       __HIP_MEMORY_SCOPE_WORKGROUP);
                } else {
                    lds_spin(&ready[1], t);
                }
            }
            asm volatile("" ::: "memory");
            // ---- issue h1[t-1] loads ----
            const bfreg* s1 = Hb1 + (size_t)t * BH;
            #pragma unroll
            for (int i = 0; i < ECNT; ++i) {
                const int ks = kq + 4 * (16 + i);        // 64..127
                const int cb = (ks - 64) * 2 + k8;
                ev[i] = *(const bf16x8*)(s1 + (size_t)cb * 512 + rowA * 8);
            }
            __builtin_amdgcn_sched_barrier(0);
        }

        // ---- MFMA blocks (one 32x32x16 per k-step) ----
        if (!LAYER) {
            #pragma unroll
            for (int i = 0; i < ECNT; ++i) {
                const int ks = kq + 4 * i;
                const bf16x8 w = *(const bf16x8*)(lW + ((size_t)ks * 64 + l) * 8);
                acc = __builtin_amdgcn_mfma_f32_32x32x16_bf16(ev[i], w, acc, 0, 0, 0);
            }
            #pragma unroll
            for (int i = 0; i < LCNT; ++i) {
                const int ks = kq + 4 * (8 + i);
                const bf16x8 w = *(const bf16x8*)(lW + ((size_t)ks * 64 + l) * 8);
                acc = __builtin_amdgcn_mfma_f32_32x32x16_bf16(av[i], w, acc, 0, 0, 0);
            }
        } else {
            #pragma unroll
            for (int i = 0; i < LCNT; ++i) {
                const int ks = kq + 4 * i;
                const bf16x8 w = *(const bf16x8*)(lW + ((size_t)ks * 64 + l) * 8);
                acc = __builtin_amdgcn_mfma_f32_32x32x16_bf16(av[i], w, acc, 0, 0, 0);
            }
            #pragma unroll
            for (int i = 0; i < ECNT; ++i) {
                const int ks = kq + 4 * (16 + i);
                const bf16x8 w = *(const bf16x8*)(lW + ((size_t)ks * 64 + l) * 8);
                acc = __builtin_amdgcn_mfma_f32_32x32x16_bf16(ev[i], w, acc, 0, 0, 0);
            }
        }

        // ---- two-phase K-partial reduction in LDS ----
        if (wid >= 4) {
            float* slot = gatebuf + (kq - 2) * (32 * 68);
            #pragma unroll
            for (int q = 0; q < 4; ++q) {
                f32x4 v = { acc[4 * q], acc[4 * q + 1], acc[4 * q + 2], acc[4 * q + 3] };
                *(f32x4*)(slot + rr * 68 + m * 32 + 8 * q + boff) = v;
            }
        }
        __syncthreads();   // [R1]
        if (wid < 4) {
            float* slot = gatebuf + kq * (32 * 68);
            #pragma unroll
            for (int q = 0; q < 4; ++q) {
                float* pp = slot + rr * 68 + m * 32 + 8 * q + boff;
                f32x4 v = *(f32x4*)pp;
                v[0] += acc[4 * q];     v[1] += acc[4 * q + 1];
                v[2] += acc[4 * q + 2]; v[3] += acc[4 * q + 3];
                *(f32x4*)pp = v;
            }
        }
        __syncthreads();   // [A] gates ready

        // ---- epilogue + direct per-wave publish ----
        {
            const int uo = tid & 7, b = tid >> 3;
            float* g0 = gatebuf;
            float* g1 = gatebuf + 32 * 68;
            const float fv = g0[uo * 68 + b]        + g1[uo * 68 + b]        + lbias[uo];
            const float iv = g0[(8 + uo) * 68 + b]  + g1[(8 + uo) * 68 + b]  + lbias[8 + uo];
            const float ov = g0[(16 + uo) * 68 + b] + g1[(16 + uo) * 68 + b] + lbias[16 + uo];
            const float gv = g0[(24 + uo) * 68 + b] + g1[(24 + uo) * 68 + b] + lbias[24 + uo];
            const float c = cbuf[uo * 68 + b];
            const float fg = sigf(fv), ig = sigf(iv), og = sigf(ov);
            const float gg = tanhfast(gv);
            const float cn = fg * c + ig * gg;
            cbuf[uo * 68 + b] = cn;
            const bfreg hv = (bfreg)(og * tanhfast(cn));
            unsigned short hs;
            __builtin_memcpy(&hs, &hv, 2);
            const unsigned hw = hs;
            bfreg* dp = Hme + (size_t)(t + 1) * BH + rg * 512 + tid;
            asm volatile("global_store_short %0, %1, off sc0 sc1"
                         :: "v"(dp), "v"(hw) : "memory");
            asm volatile("s_waitcnt vmcnt(0)" ::: "memory");
        }
        if (l == 0)
            __hip_atomic_fetch_add(done, 1, __ATOMIC_ACQ_REL,
                                   __HIP_MEMORY_SCOPE_WORKGROUP);
        if (wid == 1) {
            // publisher: all 8 waves' h stores acked -> bump this WG's sub line
            while (__hip_atomic_load(done, __ATOMIC_ACQUIRE,
                                     __HIP_MEMORY_SCOPE_WORKGROUP) < 8 * (t + 1))
                __builtin_amdgcn_s_sleep(1);
            if (l == 0)
                __hip_atomic_fetch_add(mysub + (size_t)t * 128 + (rg >> 4) * 16, 1u,
                                       __ATOMIC_RELAXED, __HIP_MEMORY_SCOPE_AGENT);
        }
    }
}

__global__ __launch_bounds__(THREADS, 2)
void lstm_scan(const bfreg* __restrict__ Pw0, const bfreg* __restrict__ Pw1,
               const float* __restrict__ bias0, const float* __restrict__ bias1,
               const bfreg* __restrict__ x_pk,
               bfreg* __restrict__ Hb0, bfreg* __restrict__ Hb1,
               unsigned* __restrict__ sub0, unsigned* __restrict__ sub1)
{
    extern __shared__ char smem[];
    const int wgid = blockIdx.x;
    const int rg = wgid >> 1;
    if (wgid & 1)
        scan_layer<1>(Pw1, bias1, x_pk, Hb0, Hb1, sub0, sub1, rg, smem);
    else
        scan_layer<0>(Pw0, bias0, x_pk, Hb0, Hb1, sub0, sub1, rg, smem);
}

// ---------- FC head ----------
__global__ void fc_gemm(const bfreg* __restrict__ Hb1, const bfreg* __restrict__ Wb,
                        const float* __restrict__ bias, float* __restrict__ out)
{
    const int lane = threadIdx.x & 63;
    const int wid = threadIdx.x >> 6;
    const int cl = lane & 15, kg = lane >> 4;
    const int mbase = blockIdx.y * 64 + (wid >> 1) * 32;
    const int nbase = blockIdx.x * 64 + (wid & 1) * 32;
    const int t = mbase >> 6;
    const int b0 = mbase & 63;
    const bfreg* pa0 = Hb1 + (size_t)(t + 1) * BH + (size_t)kg * 512 + (b0 + cl) * 8;
    const bfreg* pa1 = pa0 + 16 * 8;
    const bfreg* pb0 = Wb + (size_t)(nbase + cl) * HDIM + kg * 8;
    const bfreg* pb1 = pb0 + (size_t)16 * HDIM;
    f32x4 acc[2][2] = {};
    #pragma unroll 4
    for (int k = 0; k < HDIM; k += 32) {
        const size_t co = (size_t)(k >> 3) * 512;
        const bf16x8 av0 = *(const bf16x8*)(pa0 + co);
        const bf16x8 av1 = *(const bf16x8*)(pa1 + co);
        const bf16x8 bv0 = *(const bf16x8*)(pb0 + k);
        const bf16x8 bv1 = *(const bf16x8*)(pb1 + k);
        acc[0][0] = __builtin_amdgcn_mfma_f32_16x16x32_bf16(av0, bv0, acc[0][0], 0, 0, 0);
        acc[0][1] = __builtin_amdgcn_mfma_f32_16x16x32_bf16(av0, bv1, acc[0][1], 0, 0, 0);
        acc[1][0] = __builtin_amdgcn_mfma_f32_16x16x32_bf16(av1, bv0, acc[1][0], 0, 0, 0);
        acc[1][1] = __builtin_amdgcn_mfma_f32_16x16x32_bf16(av1, bv1, acc[1][1], 0, 0, 0);
    }
    #pragma unroll
    for (int mi = 0; mi < 2; ++mi)
        #pragma unroll
        for (int ni = 0; ni < 2; ++ni)
            #pragma unroll
            for (int r = 0; r < 4; ++r) {
                const int row = mbase + mi * 16 + kg * 4 + r;
                const int col = nbase + ni * 16 + cl;
                out[(size_t)row * OUTDIM + col] = acc[mi][ni][r] + bias[col];
            }
}

extern "C" void kernel_launch(void* const* d_in, const int* in_sizes, int n_in,
                              void* d_out, int out_size, void* d_ws, size_t ws_size,
                              hipStream_t stream)
{
    const float* x     = (const float*)d_in[0];
    const float* l0_Wx = (const float*)d_in[1];
    const float* l0_Uh = (const float*)d_in[2];
    const float* l0_bx = (const float*)d_in[3];
    const float* l0_bh = (const float*)d_in[4];
    const float* l1_Wx = (const float*)d_in[5];
    const float* l1_Uh = (const float*)d_in[6];
    const float* l1_bx = (const float*)d_in[7];
    const float* l1_bh = (const float*)d_in[8];
    const float* fc_W  = (const float*)d_in[9];
    const float* fc_b  = (const float*)d_in[10];
    (void)in_sizes; (void)n_in; (void)out_size; (void)ws_size;

    char* p = (char*)d_ws;
    size_t off = 0;
    auto take = [&](size_t bytes) {
        void* r = p + off;
        off = (off + bytes + 255) & ~(size_t)255;
        return r;
    };

    bfreg* x_pk  = (bfreg*)take((size_t)SDIM * BDIM * INDIM * 2);
    bfreg* Pw0   = (bfreg*)take((size_t)128 * 96 * 512 * 2);    // [wg][ks16][64 lanes x 8]
    bfreg* Pw1   = (bfreg*)take((size_t)128 * 128 * 512 * 2);
    bfreg* fcWb  = (bfreg*)take((size_t)OUTDIM * HDIM * 2);
    float* bias0 = (float*)take((size_t)4 * HDIM * 4);
    float* bias1 = (float*)take((size_t)4 * HDIM * 4);
    bfreg* Hb0   = (bfreg*)take((size_t)(SDIM + 1) * BH * 2);
    bfreg* Hb1   = (bfreg*)take((size_t)(SDIM + 1) * BH * 2);
    unsigned* sub0 = (unsigned*)take((size_t)SDIM * 128 * 4);   // [t][8 lines x 16]
    unsigned* sub1 = (unsigned*)take((size_t)SDIM * 128 * 4);

    // deterministic per-call init
    hipMemsetAsync(Hb0, 0, (size_t)BH * 2, stream);
    hipMemsetAsync(Hb1, 0, (size_t)BH * 2, stream);
    hipMemsetAsync(sub0, 0, (size_t)SDIM * 128 * 4, stream);
    hipMemsetAsync(sub1, 0, (size_t)SDIM * 128 * 4, stream);

    pack_x<<<4096, 256, 0, stream>>>(x_pk, x);
    cvt_bf16<<<512, 256, 0, stream>>>(fcWb, fc_W, OUTDIM * HDIM / 4);
    pack_w<<<3072, 256, 0, stream>>>(Pw0, l0_Wx, l0_Uh, INDIM, HDIM);
    pack_w<<<4096, 256, 0, stream>>>(Pw1, l1_Wx, l1_Uh, HDIM, HDIM);
    bias_combine<<<16, 256, 0, stream>>>(bias0, l0_bx, l0_bh, bias1, l1_bx, l1_bh);

    const int smem_bytes = 128 * 1024 + 2 * 32 * 68 * 4 + 8 * 68 * 4 + 32 * 4 + 16;
    hipFuncSetAttribute((const void*)lstm_scan,
                        hipFuncAttributeMaxDynamicSharedMemorySize, smem_bytes);
    lstm_scan<<<NWG, THREADS, smem_bytes, stream>>>(Pw0, Pw1, bias0, bias1,
                                                    x_pk, Hb0, Hb1, sub0, sub1);

    fc_gemm<<<dim3(OUTDIM / 64, SDIM * BDIM / 64), 256, 0, stream>>>(
        Hb1, fcWb, fc_b, (float*)d_out);
}

// Round 15
// 2723.027 us; speedup vs baseline: 1.6807x; 1.1814x over previous
//
#include <hip/hip_runtime.h>
#include <hip/hip_bf16.h>

#define SDIM 512
#define BDIM 64
#define INDIM 512
#define HDIM 1024
#define OUTDIM 512
#define NWG 256
#define THREADS 512
#define BH (BDIM * HDIM)

typedef __bf16 bfreg;
typedef bfreg bf16x8 __attribute__((ext_vector_type(8)));
typedef bfreg bf16x4 __attribute__((ext_vector_type(4)));
typedef float f32x4 __attribute__((ext_vector_type(4)));
typedef float f32x16 __attribute__((ext_vector_type(16)));

__device__ __forceinline__ float sigf(float x) { return 1.f / (1.f + __expf(-x)); }
__device__ __forceinline__ float tanhfast(float x) { return 1.f - 2.f / (__expf(2.f * x) + 1.f); }

// ---------- preamble kernels ----------

__global__ void cvt_bf16(bfreg* __restrict__ dst, const float* __restrict__ src, int n4)
{
    for (int i = blockIdx.x * blockDim.x + threadIdx.x; i < n4; i += gridDim.x * blockDim.x) {
        const float4 v = *(const float4*)(src + (size_t)i * 4);
        bf16x4 o;
        o[0] = (bfreg)v.x; o[1] = (bfreg)v.y; o[2] = (bfreg)v.z; o[3] = (bfreg)v.w;
        *(bf16x4*)(dst + (size_t)i * 4) = o;
    }
}

__global__ void bias_combine(float* __restrict__ b0, const float* __restrict__ bx0,
                             const float* __restrict__ bh0,
                             float* __restrict__ b1, const float* __restrict__ bx1,
                             const float* __restrict__ bh1)
{
    int i = blockIdx.x * blockDim.x + threadIdx.x;
    if (i < 4 * HDIM) {
        b0[i] = bx0[i] + bh0[i];
        b1[i] = bx1[i] + bh1[i];
    }
}

// Pack x [S][B][IN] fp32 -> chunked bf16 [S][IN/8][B][8]
__global__ void pack_x(bfreg* __restrict__ dst, const float* __restrict__ src)
{
    const int total = SDIM * (INDIM / 8) * BDIM;      // 16B chunks
    for (int idx = blockIdx.x * blockDim.x + threadIdx.x; idx < total;
         idx += gridDim.x * blockDim.x) {
        const int b = idx & (BDIM - 1);
        const int r = idx >> 6;
        const int kb = r & (INDIM / 8 - 1);
        const int t = r >> 6;
        const float* s = src + ((size_t)t * BDIM + b) * INDIM + kb * 8;
        bfreg* d = dst + (size_t)idx * 8;
        #pragma unroll
        for (int j = 0; j < 8; ++j) d[j] = (bfreg)s[j];
    }
}

// Pack W = [Wx | Uh] (row-major fp32) into per-WG 32x32x16 MFMA B-fragment
// order, bf16. dst chunk idx = (wg*KST16 + ks)*64 + lane ; chunk = 8 bf16.
// rr = lane&31; g = rr>>3; uo = rr&7; row = g*HDIM + wg*8 + uo;
// k = ks*16 + (lane>>5)*8 + j.
__global__ void pack_w(bfreg* __restrict__ dst, const float* __restrict__ Wx,
                       const float* __restrict__ Uh, int K0, int KH)
{
    const int KST16 = (K0 + KH) / 16;
    const int total = 128 * KST16 * 64;
    for (int idx = blockIdx.x * blockDim.x + threadIdx.x; idx < total;
         idx += gridDim.x * blockDim.x) {
        const int lane = idx & 63;
        int rem = idx >> 6;
        const int ks = rem % KST16;
        const int wg = rem / KST16;
        const int rr = lane & 31;
        const int g = rr >> 3, uo = rr & 7;
        const int row = g * HDIM + wg * 8 + uo;
        const int k = ks * 16 + (lane >> 5) * 8;
        const float* s = (k < K0) ? Wx + (size_t)row * K0 + k
                                  : Uh + (size_t)row * KH + (k - K0);
        bfreg* d = dst + (size_t)idx * 8;
        #pragma unroll
        for (int j = 0; j < 8; ++j) d[j] = (bfreg)s[j];
    }
}

// ---------- sync helpers (contention-isolated tree, r10/r12 design) ----------
// Producers: publisher wave RMWs 1 of 8 sub lines (16 producers each; only
// the aggregator reads these). Aggregator (WG rg==0, wave 2): lanes 0-7 poll
// the 8 sub lines, lane0 stores gen[t]=1. Consumers: poller wave spins on
// the read-only gen line; other waves spin on an LDS ready flag.
// This traffic-class separation (RMW lines vs consumer-poll line) beat all
// flatter topologies (r11 push-tree, r13 per-wave, r14 direct-poll).

__device__ __forceinline__ void wait_gen(const unsigned* g)
{
    while (__hip_atomic_load(g, __ATOMIC_RELAXED, __HIP_MEMORY_SCOPE_AGENT) == 0u)
        __builtin_amdgcn_s_sleep(1);
}

__device__ __forceinline__ void lds_spin(int* r, int target)
{
    while (__hip_atomic_load(r, __ATOMIC_ACQUIRE, __HIP_MEMORY_SCOPE_WORKGROUP) < target)
        __builtin_amdgcn_s_sleep(1);
}

// ---------- persistent 2-layer LSTM scan: 32x32x16 MFMA core ----------
// 256 WGs x 512 threads, 1 WG/CU. layer = wgid&1, rg = wgid>>1 (8 h-units =
// 32 gate rows = one 32-wide ntile). Waves: wid = kq*2 + m ; m = 32-row batch
// half, kq = strided K-quarter (ks = kq + 4*i). Each wave: one 32x32 output
// tile, acc = f32x16. 4 K-partials -> two-phase LDS reduction (kq>=2 store,
// barrier, kq<2 RMW-add, barrier) -> epilogue.
// A-frag: row = m*32+(lane&31), k-octet = lane>>5. B from LDS packed order.
// C/D: col(rr) = lane&31, row(b in 32) = (r&3)+8*(r>>2)+4*(lane>>5).
template<int LAYER>
__device__ __forceinline__ void scan_layer(
    const bfreg* __restrict__ Pw, const float* __restrict__ biasL,
    const bfreg* __restrict__ x_pk,
    bfreg* __restrict__ Hb0, bfreg* __restrict__ Hb1,
    unsigned* __restrict__ sub0, unsigned* __restrict__ sub1,
    unsigned* __restrict__ gen0, unsigned* __restrict__ gen1,
    const int rg, char* smem)
{
    constexpr int KST16 = LAYER ? 128 : 96;
    constexpr int ECNT = LAYER ? 16 : 8;     // L0: x (ks<32); L1: h1 (ks>=64)
    constexpr int LCNT = 16;                 // L0: h0 (ks 32..95); L1: h0 (ks<64)

    const int tid = threadIdx.x;
    const int l = tid & 63;
    const int wid = tid >> 6;
    const int m = wid & 1;
    const int kq = wid >> 1;

    bfreg* lW = (bfreg*)smem;
    float* gatebuf = (float*)(smem + 128 * 1024);  // [2][32][68]
    float* cbuf = gatebuf + 2 * 32 * 68;           // [8][68]
    float* lbias = cbuf + 8 * 68;                  // [32]
    int* ready = (int*)(lbias + 32);               // [0],[1] gates, [2] done

    {
        const float4* wsrc = (const float4*)(Pw + (size_t)rg * ((size_t)KST16 * 512));
        float4* wdst = (float4*)lW;
        for (int i = tid; i < KST16 * 64; i += THREADS) wdst[i] = wsrc[i];
    }
    if (tid < 32) lbias[tid] = biasL[(tid >> 3) * HDIM + rg * 8 + (tid & 7)];
    if (tid < 3) ready[tid] = 0;
    for (int i = tid; i < 8 * 68; i += THREADS) cbuf[i] = 0.f;
    __syncthreads();

    const int rowA = m * 32 + (l & 31);
    const int k8 = l >> 5;
    const int rr = l & 31;
    const int boff = 4 * (l >> 5);

    unsigned* mysub = LAYER ? sub1 : sub0;
    unsigned* mygen = LAYER ? gen1 : gen0;
    bfreg* Hme = LAYER ? Hb1 : Hb0;
    int* done = ready + 2;

    for (int t = 0; t < SDIM; ++t) {
        f32x16 acc = {};
        bf16x8 ev[ECNT];
        bf16x8 av[LCNT];

        if (!LAYER) {
            // ---- issue x loads (no gate) ----
            const bfreg* s0 = x_pk + (size_t)t * (64 * BDIM * 8);
            #pragma unroll
            for (int i = 0; i < ECNT; ++i) {
                const int ks = kq + 4 * i;               // < 32
                const int cb = ks * 2 + k8;
                ev[i] = *(const bf16x8*)(s0 + (size_t)cb * 512 + rowA * 8);
            }
            __builtin_amdgcn_sched_barrier(0);
            // ---- gate: gen0[t-1] (poller wave 0) ----
            if (t > 0) {
                if (wid == 0) {
                    wait_gen(gen0 + (size_t)(t - 1) * 16);
                    __hip_atomic_store(&ready[0], t, __ATOMIC_RELEASE,
                                       __HIP_MEMORY_SCOPE_WORKGROUP);
                } else {
                    lds_spin(&ready[0], t);
                }
            }
            asm volatile("" ::: "memory");
            // ---- issue h0[t-1] loads ----
            const bfreg* s1 = Hb0 + (size_t)t * BH;
            #pragma unroll
            for (int i = 0; i < LCNT; ++i) {
                const int ks = kq + 4 * (8 + i);         // 32..95
                const int cb = (ks - 32) * 2 + k8;
                av[i] = *(const bf16x8*)(s1 + (size_t)cb * 512 + rowA * 8);
            }
            __builtin_amdgcn_sched_barrier(0);
        } else {
            // ---- gate: gen0[t] (L0 leads; poller wave 0) ----
            if (wid == 0) {
                wait_gen(gen0 + (size_t)t * 16);
                __hip_atomic_store(&ready[0], t + 1, __ATOMIC_RELEASE,
                                   __HIP_MEMORY_SCOPE_WORKGROUP);
            } else {
                lds_spin(&ready[0], t + 1);
            }
            asm volatile("" ::: "memory");
            // ---- issue h0[t] loads ----
            const bfreg* s0 = Hb0 + (size_t)(t + 1) * BH;
            #pragma unroll
            for (int i = 0; i < LCNT; ++i) {
                const int ks = kq + 4 * i;               // < 64
                const int cb = ks * 2 + k8;
                av[i] = *(const bf16x8*)(s0 + (size_t)cb * 512 + rowA * 8);
            }
            __builtin_amdgcn_sched_barrier(0);
            // ---- gate: gen1[t-1] (poller wave 4) ----
            if (t > 0) {
                if (wid == 4) {
                    wait_gen(gen1 + (size_t)(t - 1) * 16);
                    __hip_atomic_store(&ready[1], t, __ATOMIC_RELEASE,
                                       __HIP_MEMORY_SCOPE_WORKGROUP);
                } else {
                    lds_spin(&ready[1], t);
                }
            }
            asm volatile("" ::: "memory");
            // ---- issue h1[t-1] loads ----
            const bfreg* s1 = Hb1 + (size_t)t * BH;
            #pragma unroll
            for (int i = 0; i < ECNT; ++i) {
                const int ks = kq + 4 * (16 + i);        // 64..127
                const int cb = (ks - 64) * 2 + k8;
                ev[i] = *(const bf16x8*)(s1 + (size_t)cb * 512 + rowA * 8);
            }
            __builtin_amdgcn_sched_barrier(0);
        }

        // ---- MFMA blocks (one 32x32x16 per k-step) ----
        if (!LAYER) {
            #pragma unroll
            for (int i = 0; i < ECNT; ++i) {
                const int ks = kq + 4 * i;
                const bf16x8 w = *(const bf16x8*)(lW + ((size_t)ks * 64 + l) * 8);
                acc = __builtin_amdgcn_mfma_f32_32x32x16_bf16(ev[i], w, acc, 0, 0, 0);
            }
            #pragma unroll
            for (int i = 0; i < LCNT; ++i) {
                const int ks = kq + 4 * (8 + i);
                const bf16x8 w = *(const bf16x8*)(lW + ((size_t)ks * 64 + l) * 8);
                acc = __builtin_amdgcn_mfma_f32_32x32x16_bf16(av[i], w, acc, 0, 0, 0);
            }
        } else {
            #pragma unroll
            for (int i = 0; i < LCNT; ++i) {
                const int ks = kq + 4 * i;
                const bf16x8 w = *(const bf16x8*)(lW + ((size_t)ks * 64 + l) * 8);
                acc = __builtin_amdgcn_mfma_f32_32x32x16_bf16(av[i], w, acc, 0, 0, 0);
            }
            #pragma unroll
            for (int i = 0; i < ECNT; ++i) {
                const int ks = kq + 4 * (16 + i);
                const bf16x8 w = *(const bf16x8*)(lW + ((size_t)ks * 64 + l) * 8);
                acc = __builtin_amdgcn_mfma_f32_32x32x16_bf16(ev[i], w, acc, 0, 0, 0);
            }
        }

        // ---- two-phase K-partial reduction in LDS ----
        // phase 1: kq in {2,3} (wid>=4) store partials to slot[kq-2]
        if (wid >= 4) {
            float* slot = gatebuf + (kq - 2) * (32 * 68);
            #pragma unroll
            for (int q = 0; q < 4; ++q) {
                f32x4 v = { acc[4 * q], acc[4 * q + 1], acc[4 * q + 2], acc[4 * q + 3] };
                *(f32x4*)(slot + rr * 68 + m * 32 + 8 * q + boff) = v;
            }
        }
        __syncthreads();   // [R1]
        // phase 2: kq in {0,1} add own partial into slot[kq]
        if (wid < 4) {
            float* slot = gatebuf + kq * (32 * 68);
            #pragma unroll
            for (int q = 0; q < 4; ++q) {
                float* pp = slot + rr * 68 + m * 32 + 8 * q + boff;
                f32x4 v = *(f32x4*)pp;
                v[0] += acc[4 * q];     v[1] += acc[4 * q + 1];
                v[2] += acc[4 * q + 2]; v[3] += acc[4 * q + 3];
                *(f32x4*)pp = v;
            }
        }
        __syncthreads();   // [A] gates ready

        // ---- epilogue + direct per-wave publish ----
        {
            const int uo = tid & 7, b = tid >> 3;
            float* g0 = gatebuf;
            float* g1 = gatebuf + 32 * 68;
            const float fv = g0[uo * 68 + b]        + g1[uo * 68 + b]        + lbias[uo];
            const float iv = g0[(8 + uo) * 68 + b]  + g1[(8 + uo) * 68 + b]  + lbias[8 + uo];
            const float ov = g0[(16 + uo) * 68 + b] + g1[(16 + uo) * 68 + b] + lbias[16 + uo];
            const float gv = g0[(24 + uo) * 68 + b] + g1[(24 + uo) * 68 + b] + lbias[24 + uo];
            const float c = cbuf[uo * 68 + b];
            const float fg = sigf(fv), ig = sigf(iv), og = sigf(ov);
            const float gg = tanhfast(gv);
            const float cn = fg * c + ig * gg;
            cbuf[uo * 68 + b] = cn;
            const bfreg hv = (bfreg)(og * tanhfast(cn));
            unsigned short hs;
            __builtin_memcpy(&hs, &hv, 2);
            const unsigned hw = hs;
            bfreg* dp = Hme + (size_t)(t + 1) * BH + rg * 512 + tid;
            asm volatile("global_store_short %0, %1, off sc0 sc1"
                         :: "v"(dp), "v"(hw) : "memory");
            asm volatile("s_waitcnt vmcnt(0)" ::: "memory");
        }
        if (l == 0)
            __hip_atomic_fetch_add(done, 1, __ATOMIC_ACQ_REL,
                                   __HIP_MEMORY_SCOPE_WORKGROUP);
        if (wid == 1) {
            // publisher: all 8 waves' h stores acked -> bump this WG's sub-counter
            while (__hip_atomic_load(done, __ATOMIC_ACQUIRE,
                                     __HIP_MEMORY_SCOPE_WORKGROUP) < 8 * (t + 1))
                __builtin_amdgcn_s_sleep(1);
            if (l == 0)
                __hip_atomic_fetch_add(mysub + (size_t)t * 128 + (rg >> 4) * 16, 1u,
                                       __ATOMIC_RELAXED, __HIP_MEMORY_SCOPE_AGENT);
        }
        if (rg == 0 && wid == 2) {
            // aggregator: lanes 0-7 poll the 8 sub-counter lines; lane0 sets gen
            const unsigned* sc = mysub + (size_t)t * 128;
            while (true) {
                unsigned v = (l < 8)
                    ? __hip_atomic_load(sc + l * 16, __ATOMIC_RELAXED,
                                        __HIP_MEMORY_SCOPE_AGENT)
                    : 16u;
                if (__all(v >= 16u)) break;
                __builtin_amdgcn_s_sleep(1);
            }
            asm volatile("" ::: "memory");
            if (l == 0)
                __hip_atomic_store(mygen + (size_t)t * 16, 1u,
                                   __ATOMIC_RELEASE, __HIP_MEMORY_SCOPE_AGENT);
        }
    }
}

__global__ __launch_bounds__(THREADS, 2)
void lstm_scan(const bfreg* __restrict__ Pw0, const bfreg* __restrict__ Pw1,
               const float* __restrict__ bias0, const float* __restrict__ bias1,
               const bfreg* __restrict__ x_pk,
               bfreg* __restrict__ Hb0, bfreg* __restrict__ Hb1,
               unsigned* __restrict__ sub0, unsigned* __restrict__ sub1,
               unsigned* __restrict__ gen0, unsigned* __restrict__ gen1)
{
    extern __shared__ char smem[];
    const int wgid = blockIdx.x;
    const int rg = wgid >> 1;
    if (wgid & 1)
        scan_layer<1>(Pw1, bias1, x_pk, Hb0, Hb1, sub0, sub1, gen0, gen1, rg, smem);
    else
        scan_layer<0>(Pw0, bias0, x_pk, Hb0, Hb1, sub0, sub1, gen0, gen1, rg, smem);
}

// ---------- FC head ----------
__global__ void fc_gemm(const bfreg* __restrict__ Hb1, const bfreg* __restrict__ Wb,
                        const float* __restrict__ bias, float* __restrict__ out)
{
    const int lane = threadIdx.x & 63;
    const int wid = threadIdx.x >> 6;
    const int cl = lane & 15, kg = lane >> 4;
    const int mbase = blockIdx.y * 64 + (wid >> 1) * 32;
    const int nbase = blockIdx.x * 64 + (wid & 1) * 32;
    const int t = mbase >> 6;
    const int b0 = mbase & 63;
    const bfreg* pa0 = Hb1 + (size_t)(t + 1) * BH + (size_t)kg * 512 + (b0 + cl) * 8;
    const bfreg* pa1 = pa0 + 16 * 8;
    const bfreg* pb0 = Wb + (size_t)(nbase + cl) * HDIM + kg * 8;
    const bfreg* pb1 = pb0 + (size_t)16 * HDIM;
    f32x4 acc[2][2] = {};
    #pragma unroll 4
    for (int k = 0; k < HDIM; k += 32) {
        const size_t co = (size_t)(k >> 3) * 512;
        const bf16x8 av0 = *(const bf16x8*)(pa0 + co);
        const bf16x8 av1 = *(const bf16x8*)(pa1 + co);
        const bf16x8 bv0 = *(const bf16x8*)(pb0 + k);
        const bf16x8 bv1 = *(const bf16x8*)(pb1 + k);
        acc[0][0] = __builtin_amdgcn_mfma_f32_16x16x32_bf16(av0, bv0, acc[0][0], 0, 0, 0);
        acc[0][1] = __builtin_amdgcn_mfma_f32_16x16x32_bf16(av0, bv1, acc[0][1], 0, 0, 0);
        acc[1][0] = __builtin_amdgcn_mfma_f32_16x16x32_bf16(av1, bv0, acc[1][0], 0, 0, 0);
        acc[1][1] = __builtin_amdgcn_mfma_f32_16x16x32_bf16(av1, bv1, acc[1][1], 0, 0, 0);
    }
    #pragma unroll
    for (int mi = 0; mi < 2; ++mi)
        #pragma unroll
        for (int ni = 0; ni < 2; ++ni)
            #pragma unroll
            for (int r = 0; r < 4; ++r) {
                const int row = mbase + mi * 16 + kg * 4 + r;
                const int col = nbase + ni * 16 + cl;
                out[(size_t)row * OUTDIM + col] = acc[mi][ni][r] + bias[col];
            }
}

extern "C" void kernel_launch(void* const* d_in, const int* in_sizes, int n_in,
                              void* d_out, int out_size, void* d_ws, size_t ws_size,
                              hipStream_t stream)
{
    const float* x     = (const float*)d_in[0];
    const float* l0_Wx = (const float*)d_in[1];
    const float* l0_Uh = (const float*)d_in[2];
    const float* l0_bx = (const float*)d_in[3];
    const float* l0_bh = (const float*)d_in[4];
    const float* l1_Wx = (const float*)d_in[5];
    const float* l1_Uh = (const float*)d_in[6];
    const float* l1_bx = (const float*)d_in[7];
    const float* l1_bh = (const float*)d_in[8];
    const float* fc_W  = (const float*)d_in[9];
    const float* fc_b  = (const float*)d_in[10];
    (void)in_sizes; (void)n_in; (void)out_size; (void)ws_size;

    char* p = (char*)d_ws;
    size_t off = 0;
    auto take = [&](size_t bytes) {
        void* r = p + off;
        off = (off + bytes + 255) & ~(size_t)255;
        return r;
    };

    bfreg* x_pk  = (bfreg*)take((size_t)SDIM * BDIM * INDIM * 2);
    bfreg* Pw0   = (bfreg*)take((size_t)128 * 96 * 512 * 2);    // [wg][ks16][64 lanes x 8]
    bfreg* Pw1   = (bfreg*)take((size_t)128 * 128 * 512 * 2);
    bfreg* fcWb  = (bfreg*)take((size_t)OUTDIM * HDIM * 2);
    float* bias0 = (float*)take((size_t)4 * HDIM * 4);
    float* bias1 = (float*)take((size_t)4 * HDIM * 4);
    bfreg* Hb0   = (bfreg*)take((size_t)(SDIM + 1) * BH * 2);
    bfreg* Hb1   = (bfreg*)take((size_t)(SDIM + 1) * BH * 2);
    unsigned* sub0 = (unsigned*)take((size_t)SDIM * 128 * 4);   // [t][8 sub x 16]
    unsigned* sub1 = (unsigned*)take((size_t)SDIM * 128 * 4);
    unsigned* gen0 = (unsigned*)take((size_t)SDIM * 16 * 4);    // [t][16]
    unsigned* gen1 = (unsigned*)take((size_t)SDIM * 16 * 4);

    // deterministic per-call init
    hipMemsetAsync(Hb0, 0, (size_t)BH * 2, stream);
    hipMemsetAsync(Hb1, 0, (size_t)BH * 2, stream);
    hipMemsetAsync(sub0, 0, (size_t)SDIM * 128 * 4, stream);
    hipMemsetAsync(sub1, 0, (size_t)SDIM * 128 * 4, stream);
    hipMemsetAsync(gen0, 0, (size_t)SDIM * 16 * 4, stream);
    hipMemsetAsync(gen1, 0, (size_t)SDIM * 16 * 4, stream);

    pack_x<<<4096, 256, 0, stream>>>(x_pk, x);
    cvt_bf16<<<512, 256, 0, stream>>>(fcWb, fc_W, OUTDIM * HDIM / 4);
    pack_w<<<3072, 256, 0, stream>>>(Pw0, l0_Wx, l0_Uh, INDIM, HDIM);
    pack_w<<<4096, 256, 0, stream>>>(Pw1, l1_Wx, l1_Uh, HDIM, HDIM);
    bias_combine<<<16, 256, 0, stream>>>(bias0, l0_bx, l0_bh, bias1, l1_bx, l1_bh);

    const int smem_bytes = 128 * 1024 + 2 * 32 * 68 * 4 + 8 * 68 * 4 + 32 * 4 + 16;
    hipFuncSetAttribute((const void*)lstm_scan,
                        hipFuncAttributeMaxDynamicSharedMemorySize, smem_bytes);
    lstm_scan<<<NWG, THREADS, smem_bytes, stream>>>(Pw0, Pw1, bias0, bias1,
                                                    x_pk, Hb0, Hb1,
                                                    sub0, sub1, gen0, gen1);

    fc_gemm<<<dim3(OUTDIM / 64, SDIM * BDIM / 64), 256, 0, stream>>>(
        Hb1, fcWb, fc_b, (float*)d_out);
}